// Round 2
// baseline (123.271 us; speedup 1.0000x reference)
//
#include <hip/hip_runtime.h>
#include <hip/hip_bf16.h>

#define D 128
#define NOPS 4
#define BS_STRIDE 136  // padded bf16 row stride: 272 B = 16B-aligned, 2-way bank alias (free)

typedef __attribute__((ext_vector_type(8))) short short8;
typedef __attribute__((ext_vector_type(4))) float float4_t;

// ---------------------------------------------------------------------------
// Kernel 1: fold the 4 candidate ops into one combined matrix/bias.
//   Wc[f][d] = sum_o weights[o] * W[o][f][d]   (stored bf16)
//   bc[f]    = sum_o weights[o] * b[o][f]      (stored fp32)
// ---------------------------------------------------------------------------
__global__ void combine_kernel(const float* __restrict__ W,
                               const float* __restrict__ b,
                               const float* __restrict__ wts,
                               __hip_bfloat16* __restrict__ Wc,
                               float* __restrict__ bc) {
    int idx = blockIdx.x * blockDim.x + threadIdx.x;
    float w0 = wts[0], w1 = wts[1], w2 = wts[2], w3 = wts[3];
    if (idx < D * D) {
        float v = w0 * W[idx] + w1 * W[D * D + idx]
                + w2 * W[2 * D * D + idx] + w3 * W[3 * D * D + idx];
        Wc[idx] = __float2bfloat16(v);
    }
    if (idx < D) {
        bc[idx] = w0 * b[idx] + w1 * b[D + idx] + w2 * b[2 * D + idx] + w3 * b[3 * D + idx];
    }
}

// ---------------------------------------------------------------------------
// Kernel 2: y[m][f] = sum_d x[m][d] * Wc[f][d] + bc[f]
// M = B*S = 131072 rows. 256 threads = 4 waves/block; each wave does a
// 16-row x 128-col slab via mfma_f32_16x16x32_bf16 (4 K-steps x 8 N-tiles).
// Wc staged once per block into LDS (padded rows). A-frags straight from
// global (fp32) with in-register bf16 convert.
// ---------------------------------------------------------------------------
__device__ inline short8 cvt8_bf16(float4_t a, float4_t b) {
    union { short8 s; __hip_bfloat16 h[8]; } u;
    u.h[0] = __float2bfloat16(a[0]);
    u.h[1] = __float2bfloat16(a[1]);
    u.h[2] = __float2bfloat16(a[2]);
    u.h[3] = __float2bfloat16(a[3]);
    u.h[4] = __float2bfloat16(b[0]);
    u.h[5] = __float2bfloat16(b[1]);
    u.h[6] = __float2bfloat16(b[2]);
    u.h[7] = __float2bfloat16(b[3]);
    return u.s;
}

__global__ __launch_bounds__(256) void gemm_kernel(const float* __restrict__ x,
                                                   const __hip_bfloat16* __restrict__ Wc,
                                                   const float* __restrict__ bc,
                                                   float* __restrict__ y,
                                                   int M) {
    __shared__ __align__(16) __hip_bfloat16 Bs[D * BS_STRIDE];  // 34816 B

    const int tid  = threadIdx.x;
    const int lane = tid & 63;
    const int wave = tid >> 6;

    // ---- stage Wc -> LDS (2048 chunks of 8 bf16; coalesced 16B loads) ----
    #pragma unroll
    for (int i = 0; i < 8; i++) {
        int c  = i * 256 + tid;      // 0..2047
        int n  = c >> 4;             // row (0..127)
        int ko = (c & 15) << 3;      // k offset (0,8,...,120)
        short8 v = *(const short8*)((const short*)Wc + n * D + ko);
        *(short8*)((short*)Bs + n * BS_STRIDE + ko) = v;
    }
    __syncthreads();

    const int m0 = (blockIdx.x * 4 + wave) * 16;  // 16 rows per wave
    if (m0 >= M) return;

    const int row  = lane & 15;   // A: m within tile / B: n within tile / C: col
    const int quad = lane >> 4;

    float4_t acc[8];
    #pragma unroll
    for (int i = 0; i < 8; i++) acc[i] = (float4_t)(0.f);

    #pragma unroll
    for (int ks = 0; ks < 4; ks++) {
        // A frag: A[m = row][k = ks*32 + quad*8 + j], j=0..7  (fp32 -> bf16)
        const float* ap = x + (size_t)(m0 + row) * D + ks * 32 + quad * 8;
        float4_t a0 = *(const float4_t*)ap;
        float4_t a1 = *(const float4_t*)(ap + 4);
        short8 afrag = cvt8_bf16(a0, a1);

        const short* bp = (const short*)Bs + ks * 32 + quad * 8;
        #pragma unroll
        for (int nt = 0; nt < 8; nt++) {
            // B frag: B[k][n] = Wc[n = nt*16+row][k = ks*32 + quad*8 + j]
            short8 bfrag = *(const short8*)(bp + (nt * 16 + row) * BS_STRIDE);
            acc[nt] = __builtin_amdgcn_mfma_f32_16x16x32_bf16(afrag, bfrag, acc[nt], 0, 0, 0);
        }
    }

    // ---- epilogue: C/D layout col = lane&15, row = quad*4 + reg ----
    #pragma unroll
    for (int nt = 0; nt < 8; nt++) {
        int col = nt * 16 + row;
        float bias = bc[col];
        #pragma unroll
        for (int r = 0; r < 4; r++) {
            int m = m0 + quad * 4 + r;
            y[(size_t)m * D + col] = acc[nt][r] + bias;
        }
    }
}

extern "C" void kernel_launch(void* const* d_in, const int* in_sizes, int n_in,
                              void* d_out, int out_size, void* d_ws, size_t ws_size,
                              hipStream_t stream) {
    const float* x   = (const float*)d_in[0];   // (B,S,D) fp32
    const float* W   = (const float*)d_in[1];   // (NOPS,D,D) fp32
    const float* b   = (const float*)d_in[2];   // (NOPS,D) fp32
    const float* wts = (const float*)d_in[3];   // (NOPS,) fp32
    float* y = (float*)d_out;

    __hip_bfloat16* Wc = (__hip_bfloat16*)d_ws;
    float* bc = (float*)((char*)d_ws + D * D * sizeof(__hip_bfloat16));

    combine_kernel<<<(D * D + 255) / 256, 256, 0, stream>>>(W, b, wts, Wc, bc);

    const int M = in_sizes[0] / D;  // B*S = 131072
    gemm_kernel<<<M / 64, 256, 0, stream>>>(x, Wc, bc, y, M);
}